// Round 1
// 122.613 us; speedup vs baseline: 1.0551x; 1.0551x over previous
//
#include <hip/hip_runtime.h>
#include <math.h>

#define LL 8
#define AA 4
#define DD 256
#define KF 129            // frequencies 0..128
#define KH 128            // complex-path frequencies 0..127; k=128 handled as real
#define NCHUNK 512
#define CLEN 32           // 16384 / 512
#define NE 44             // stored entries per operator (rows 1..8)
#define NE1 45            // including implicit row 0 (= e0)
#define LSTR 45           // LDS stride (float2 / float) in kreduce: odd -> conflict-free b64

#define IDX(l,l1) ((((l)*((l)+1))/2) + (l1))

// ws layout in floats (~23.2 MB)
#define Q_OFF      0
#define OPST_OFF   (32 * KF * 2)                         // 8,256
#define OPS128_OFF (OPST_OFF + KH * NCHUNK * NE * 2)     // + 5,767,168
#define V_OFF      (OPS128_OFF + NCHUNK * NE)            // + 22,528

// ---------------- kernel 0: Q[l][c][k] = (2*sigmoid(logit)-1) * DFT_k(softmax(hash_emb[l,c,:])) ----
__global__ __launch_bounds__(256) void kq(const float* __restrict__ hemb,
                                          const float* __restrict__ slog,
                                          float* __restrict__ Q) {
  const int b = blockIdx.x;   // b = l*4 + c
  const int t = threadIdx.x;  // 0..255
  __shared__ float sh[DD];
  __shared__ float red[256];
  __shared__ float2 tw[256];
  {
    float sn, cs;
    __sincosf((float)t * (-0.0245436926061702596754894014319f), &sn, &cs); // -2*pi/256
    tw[t] = make_float2(cs, sn);
  }
  float h = hemb[b * DD + t];
  red[t] = h; __syncthreads();
  for (int off = 128; off > 0; off >>= 1) {
    if (t < off) red[t] = fmaxf(red[t], red[t + off]);
    __syncthreads();
  }
  float mx = red[0]; __syncthreads();
  float e = expf(h - mx);
  red[t] = e; __syncthreads();
  for (int off = 128; off > 0; off >>= 1) {
    if (t < off) red[t] += red[t + off];
    __syncthreads();
  }
  float s = red[0];
  sh[t] = e / s;
  __syncthreads();
  if (t < KF) {
    float cr = 0.0f, ci = 0.0f;
    for (int j = 0; j < DD; ++j) {
      const int m = (t * j) & 255;
      const float2 w = tw[m];
      const float p = sh[j];
      cr = fmaf(p, w.x, cr);
      ci = fmaf(p, w.y, ci);
    }
    const float sl = slog[b];
    const float sg = 1.0f / (1.0f + expf(-sl));
    const float q = fmaf(2.0f, sg, -1.0f);   // 2*sigmoid - 1
    Q[(b * KF + t) * 2 + 0] = q * cr;
    Q[(b * KF + t) * 2 + 1] = q * ci;
  }
}

// ---------------- complex per-step operator update -------------------------------------------
template <int CC>
__device__ __forceinline__ void step_update(float (&Gr)[NE1], float (&Gi)[NE1],
                                            const float (&Qr)[LL][AA], const float (&Qi)[LL][AA],
                                            const float (&z)[LL + 1]) {
#pragma unroll
  for (int l = LL; l >= 1; --l) {          // descending: row l reads OLD row l-1
    const float zl = z[l];
    const float oz = 1.0f - zl;
    const float zqr = zl * Qr[l - 1][CC];
    const float zqi = zl * Qi[l - 1][CC];
    Gr[IDX(l, l)] *= oz;
    Gi[IDX(l, l)] *= oz;
#pragma unroll
    for (int l1 = 0; l1 < l; ++l1) {
      const float hr = Gr[IDX(l - 1, l1)];
      const float hi = Gi[IDX(l - 1, l1)];
      float gr = oz * Gr[IDX(l, l1)];
      float gi = oz * Gi[IDX(l, l1)];
      gr = fmaf(zqr, hr, gr);
      gr = fmaf(-zqi, hi, gr);
      gi = fmaf(zqr, hi, gi);
      gi = fmaf(zqi, hr, gi);
      Gr[IDX(l, l1)] = gr;
      Gi[IDX(l, l1)] = gi;
    }
  }
}

// ---------------- kernel 1: chunk transfer operators (transposed output [k][p][e]) -----------
// blocks 0..1023: (chunk p = blk>>1, k = (blk&1)*64 + tid), complex path
// blocks 1024..1031: k=128 real path, lane = chunk; output [p][e]
__global__ __launch_bounds__(64) void kchunk(const int* __restrict__ seq,
                                             const float* __restrict__ Q,
                                             float* __restrict__ opsT,
                                             float* __restrict__ ops128T) {
  const int blk = blockIdx.x;
  const int t = threadIdx.x;
  __shared__ __align__(16) float sbuf[64 * NE * 2];   // 22528 B staging
  if (blk < NCHUNK * 2) {
    const int p = blk >> 1;
    const int k = (blk & 1) * 64 + t;    // 0..127
    float Qr[LL][AA], Qi[LL][AA];
    const float2* Q2 = (const float2*)Q;
#pragma unroll
    for (int lc = 0; lc < LL * AA; ++lc) {
      const float2 q = Q2[lc * KF + k];
      Qr[lc >> 2][lc & 3] = q.x;
      Qi[lc >> 2][lc & 3] = q.y;
    }
    float Gr[NE1], Gi[NE1];
#pragma unroll
    for (int e = 0; e < NE1; ++e) { Gr[e] = 0.0f; Gi[e] = 0.0f; }
#pragma unroll
    for (int l = 0; l <= LL; ++l) Gr[IDX(l, l)] = 1.0f;   // G = I

    const int base = p * CLEN;
    const int myc = seq[base + (t & 31)];   // whole chunk in registers, lane-parallel
    for (int s2 = 0; s2 < CLEN; ++s2) {
      const int i = base + s2;
      const int c = __builtin_amdgcn_readlane(myc, s2);   // SGPR -> scalar switch, no load
      const float inv = 1.0f / (float)(i + 1);
      float z[LL + 1];
      z[0] = 0.0f;
#pragma unroll
      for (int l = 1; l <= LL; ++l) z[l] = (l <= i + 1) ? (float)l * inv : 0.0f;
      switch (c) {
        case 0:  step_update<0>(Gr, Gi, Qr, Qi, z); break;
        case 1:  step_update<1>(Gr, Gi, Qr, Qi, z); break;
        case 2:  step_update<2>(Gr, Gi, Qr, Qi, z); break;
        default: step_update<3>(Gr, Gi, Qr, Qi, z); break;
      }
    }
    // stage and write transposed: opsT[k][p][e] (352 B contiguous per (k,p))
    float2* ob = (float2*)sbuf;
#pragma unroll
    for (int e = 0; e < NE; ++e) ob[t * NE + e] = make_float2(Gr[e + 1], Gi[e + 1]);
    __syncthreads();
    const int k0 = (blk & 1) * 64;
    const float4* lb = (const float4*)sbuf;
    for (int it = 0; it < 22; ++it) {          // 64 segs * 22 float4 = 1408
      const int gid = it * 64 + t;
      const int sseg = gid / 22;
      const int u = gid - sseg * 22;
      float4* dst = (float4*)(opsT + ((size_t)(k0 + sseg) * NCHUNK + p) * (NE * 2));
      dst[u] = lb[gid];
    }
  } else {
    // k = 128 (Nyquist): Q is real there; lane = chunk index
    const int p = (blk - NCHUNK * 2) * 64 + t;   // 0..511
    float Q8[LL][AA];
#pragma unroll
    for (int lc = 0; lc < LL * AA; ++lc) Q8[lc >> 2][lc & 3] = Q[(lc * KF + KH) * 2 + 0];
    float G[NE1];
#pragma unroll
    for (int e = 0; e < NE1; ++e) G[e] = 0.0f;
#pragma unroll
    for (int l = 0; l <= LL; ++l) G[IDX(l, l)] = 1.0f;

    const int base = p * CLEN;
    for (int s2 = 0; s2 < CLEN; ++s2) {
      const int i = base + s2;
      const int c = seq[i];                 // per-lane symbol
      const float inv = 1.0f / (float)(i + 1);
      float z[LL + 1];
      z[0] = 0.0f;
#pragma unroll
      for (int l = 1; l <= LL; ++l) z[l] = (l <= i + 1) ? (float)l * inv : 0.0f;
      float Qs[LL];
#pragma unroll
      for (int l = 0; l < LL; ++l) {
        const float qa = (c & 1) ? Q8[l][1] : Q8[l][0];
        const float qb = (c & 1) ? Q8[l][3] : Q8[l][2];
        Qs[l] = (c & 2) ? qb : qa;
      }
#pragma unroll
      for (int l = LL; l >= 1; --l) {
        const float zl = z[l], oz = 1.0f - zl;
        const float zq = zl * Qs[l - 1];
        G[IDX(l, l)] *= oz;
#pragma unroll
        for (int l1 = 0; l1 < l; ++l1) {
          float g = oz * G[IDX(l, l1)];
          G[IDX(l, l1)] = fmaf(zq, G[IDX(l - 1, l1)], g);
        }
      }
    }
    // stage and write [p][e] (176 B contiguous per p)
    float* obr = sbuf;
#pragma unroll
    for (int e = 0; e < NE; ++e) obr[t * NE + e] = G[e + 1];
    __syncthreads();
    const int pbase = (blk - NCHUNK * 2) * 64;
    const float4* lbr = (const float4*)sbuf;
    for (int it = 0; it < 11; ++it) {          // 64 segs * 11 float4 = 704
      const int gid = it * 64 + t;
      const int sseg = gid / 11;
      const int u = gid - sseg * 11;
      float4* dst = (float4*)(ops128T + (size_t)(pbase + sseg) * NE);
      dst[u] = lbr[gid];
    }
  }
}

// ---------------- kernel 2: per-frequency full reduction 512 -> v[k] -------------------------
// block k<128: complex tree; block 128: real (Nyquist) tree
__global__ __launch_bounds__(128) void kreduce(const float* __restrict__ opsT,
                                               const float* __restrict__ ops128T,
                                               float* __restrict__ v) {
  const int k = blockIdx.x;
  const int j = threadIdx.x;
  __shared__ __align__(16) float lds[128 * LSTR * 2];   // 46080 B
  if (k < KH) {
    float2* Lc = (float2*)lds;
    float Ar[NE1], Ai[NE1], Br[NE1], Bi[NE1];
    Ar[0] = 1.0f; Ai[0] = 0.0f; Br[0] = 1.0f; Bi[0] = 0.0f;
    // L1: factor-4 from global (ops 4j..4j+3), A = Op3*Op2*Op1*Op0
    {
      const float4* s0 = (const float4*)(opsT + ((size_t)k * NCHUNK + 4 * j) * (NE * 2));
#pragma unroll
      for (int u = 0; u < 22; ++u) {
        const float4 x = s0[u];
        Ar[2 * u + 1] = x.x; Ai[2 * u + 1] = x.y;
        Ar[2 * u + 2] = x.z; Ai[2 * u + 2] = x.w;
      }
      for (int jj = 1; jj < 4; ++jj) {
        const float4* sB = (const float4*)(opsT + ((size_t)k * NCHUNK + 4 * j + jj) * (NE * 2));
#pragma unroll
        for (int u = 0; u < 22; ++u) {
          const float4 x = sB[u];
          Br[2 * u + 1] = x.x; Bi[2 * u + 1] = x.y;
          Br[2 * u + 2] = x.z; Bi[2 * u + 2] = x.w;
        }
#pragma unroll
        for (int l2 = LL; l2 >= 1; --l2) {
#pragma unroll
          for (int l1 = 0; l1 <= l2; ++l1) {
            float cr = 0.0f, ci = 0.0f;
#pragma unroll
            for (int m = l1; m <= l2; ++m) {
              const float br = Br[IDX(l2, m)], bi = Bi[IDX(l2, m)];
              const float ar = Ar[IDX(m, l1)], ai = Ai[IDX(m, l1)];
              cr = fmaf(br, ar, cr); cr = fmaf(-bi, ai, cr);
              ci = fmaf(br, ai, ci); ci = fmaf(bi, ar, ci);
            }
            Ar[IDX(l2, l1)] = cr; Ai[IDX(l2, l1)] = ci;
          }
        }
      }
#pragma unroll
      for (int e = 0; e < NE; ++e) Lc[j * LSTR + e] = make_float2(Ar[e + 1], Ai[e + 1]);
    }
    __syncthreads();
    // in-place factor-2 levels: 128->64->32->16->8 (reads before barrier, writes after)
    for (int n = 64; n >= 8; n >>= 1) {
      const bool act = (j < n);
      if (act) {
#pragma unroll
        for (int e = 0; e < NE; ++e) { const float2 x = Lc[(2 * j) * LSTR + e];     Ar[e + 1] = x.x; Ai[e + 1] = x.y; }
#pragma unroll
        for (int e = 0; e < NE; ++e) { const float2 x = Lc[(2 * j + 1) * LSTR + e]; Br[e + 1] = x.x; Bi[e + 1] = x.y; }
#pragma unroll
        for (int l2 = LL; l2 >= 1; --l2) {
#pragma unroll
          for (int l1 = 0; l1 <= l2; ++l1) {
            float cr = 0.0f, ci = 0.0f;
#pragma unroll
            for (int m = l1; m <= l2; ++m) {
              const float br = Br[IDX(l2, m)], bi = Bi[IDX(l2, m)];
              const float ar = Ar[IDX(m, l1)], ai = Ai[IDX(m, l1)];
              cr = fmaf(br, ar, cr); cr = fmaf(-bi, ai, cr);
              ci = fmaf(br, ai, ci); ci = fmaf(bi, ar, ci);
            }
            Ar[IDX(l2, l1)] = cr; Ai[IDX(l2, l1)] = ci;
          }
        }
      }
      __syncthreads();
      if (act) {
#pragma unroll
        for (int e = 0; e < NE; ++e) Lc[j * LSTR + e] = make_float2(Ar[e + 1], Ai[e + 1]);
      }
      __syncthreads();
    }
    // apply 8 remaining ops to e0 (wave 0; lane l computes row l, shfl-broadcast)
    if (j < 64) {
      float sr[LL + 1], si[LL + 1];
      sr[0] = 1.0f; si[0] = 0.0f;
#pragma unroll
      for (int l = 1; l <= LL; ++l) { sr[l] = 0.0f; si[l] = 0.0f; }
      for (int g = 0; g < 8; ++g) {
        float nr = 0.0f, ni = 0.0f;
        if (j >= 1 && j <= LL) {
          const int rowbase = g * LSTR + ((j * (j + 1)) >> 1) - 1;  // entry IDX(j,0)-1
#pragma unroll
          for (int l1 = 0; l1 <= LL; ++l1) {
            if (l1 <= j) {
              const float2 bv = Lc[rowbase + l1];
              nr = fmaf(bv.x, sr[l1], nr); nr = fmaf(-bv.y, si[l1], nr);
              ni = fmaf(bv.x, si[l1], ni); ni = fmaf(bv.y, sr[l1], ni);
            }
          }
        }
#pragma unroll
        for (int l = 1; l <= LL; ++l) { sr[l] = __shfl(nr, l); si[l] = __shfl(ni, l); }
      }
      if (j == 0) { v[2 * k] = sr[LL]; v[2 * k + 1] = si[LL]; }
    }
  } else {
    // real path (k = 128)
    float* Lr = lds;
    float A[NE1], B[NE1];
    A[0] = 1.0f; B[0] = 1.0f;
    {
      const float4* s0 = (const float4*)(ops128T + (size_t)(4 * j) * NE);
#pragma unroll
      for (int u = 0; u < 11; ++u) {
        const float4 x = s0[u];
        A[4 * u + 1] = x.x; A[4 * u + 2] = x.y; A[4 * u + 3] = x.z; A[4 * u + 4] = x.w;
      }
      for (int jj = 1; jj < 4; ++jj) {
        const float4* sB = (const float4*)(ops128T + (size_t)(4 * j + jj) * NE);
#pragma unroll
        for (int u = 0; u < 11; ++u) {
          const float4 x = sB[u];
          B[4 * u + 1] = x.x; B[4 * u + 2] = x.y; B[4 * u + 3] = x.z; B[4 * u + 4] = x.w;
        }
#pragma unroll
        for (int l2 = LL; l2 >= 1; --l2) {
#pragma unroll
          for (int l1 = 0; l1 <= l2; ++l1) {
            float cr = 0.0f;
#pragma unroll
            for (int m = l1; m <= l2; ++m) cr = fmaf(B[IDX(l2, m)], A[IDX(m, l1)], cr);
            A[IDX(l2, l1)] = cr;
          }
        }
      }
#pragma unroll
      for (int e = 0; e < NE; ++e) Lr[j * LSTR + e] = A[e + 1];
    }
    __syncthreads();
    for (int n = 64; n >= 8; n >>= 1) {
      const bool act = (j < n);
      if (act) {
#pragma unroll
        for (int e = 0; e < NE; ++e) A[e + 1] = Lr[(2 * j) * LSTR + e];
#pragma unroll
        for (int e = 0; e < NE; ++e) B[e + 1] = Lr[(2 * j + 1) * LSTR + e];
#pragma unroll
        for (int l2 = LL; l2 >= 1; --l2) {
#pragma unroll
          for (int l1 = 0; l1 <= l2; ++l1) {
            float cr = 0.0f;
#pragma unroll
            for (int m = l1; m <= l2; ++m) cr = fmaf(B[IDX(l2, m)], A[IDX(m, l1)], cr);
            A[IDX(l2, l1)] = cr;
          }
        }
      }
      __syncthreads();
      if (act) {
#pragma unroll
        for (int e = 0; e < NE; ++e) Lr[j * LSTR + e] = A[e + 1];
      }
      __syncthreads();
    }
    if (j < 64) {
      float s[LL + 1];
      s[0] = 1.0f;
#pragma unroll
      for (int l = 1; l <= LL; ++l) s[l] = 0.0f;
      for (int g = 0; g < 8; ++g) {
        float nr = 0.0f;
        if (j >= 1 && j <= LL) {
          const int rowbase = g * LSTR + ((j * (j + 1)) >> 1) - 1;
#pragma unroll
          for (int l1 = 0; l1 <= LL; ++l1)
            if (l1 <= j) nr = fmaf(Lr[rowbase + l1], s[l1], nr);
        }
#pragma unroll
        for (int l = 1; l <= LL; ++l) s[l] = __shfl(nr, l);
      }
      if (j == 0) { v[2 * KH] = s[LL]; v[2 * KH + 1] = 0.0f; }
    }
  }
}

// ---------------- kernel 3: inverse real DFT of v[0..128] ------------------------------------
__global__ __launch_bounds__(256) void kdft(const float* __restrict__ v,
                                            float* __restrict__ out) {
  const int t = threadIdx.x;
  __shared__ float2 tw[256];
  __shared__ float vr[KF], vi[KF];
  {
    float sn, cs;
    __sincosf((float)t * (0.0245436926061702596754894014319f), &sn, &cs);  // +2*pi/256
    tw[t] = make_float2(cs, sn);
  }
  if (t < KF) { vr[t] = v[2 * t]; vi[t] = v[2 * t + 1]; }
  __syncthreads();
  float sum = vr[0] + ((t & 1) ? -vr[KH] : vr[KH]);
  for (int k2 = 1; k2 < KH; ++k2) {
    const int m = (t * k2) & 255;
    const float2 w = tw[m];
    sum = fmaf(2.0f * vr[k2], w.x, sum);
    sum = fmaf(-2.0f * vi[k2], w.y, sum);
  }
  out[t] = sum * (1.0f / 256.0f);
}

extern "C" void kernel_launch(void* const* d_in, const int* in_sizes, int n_in,
                              void* d_out, int out_size, void* d_ws, size_t ws_size,
                              hipStream_t stream) {
  (void)in_sizes; (void)n_in; (void)out_size; (void)ws_size;
  const int*   seq  = (const int*)d_in[0];
  const float* hemb = (const float*)d_in[1];
  const float* slog = (const float*)d_in[2];
  float* ws      = (float*)d_ws;
  float* Q       = ws + Q_OFF;
  float* opsT    = ws + OPST_OFF;
  float* ops128T = ws + OPS128_OFF;
  float* v       = ws + V_OFF;
  float* o       = (float*)d_out;

  hipLaunchKernelGGL(kq,      dim3(LL * AA), dim3(256), 0, stream, hemb, slog, Q);
  hipLaunchKernelGGL(kchunk,  dim3(NCHUNK * 2 + NCHUNK / 64), dim3(64), 0, stream, seq, Q, opsT, ops128T);
  hipLaunchKernelGGL(kreduce, dim3(KF), dim3(128), 0, stream, opsT, ops128T, v);
  hipLaunchKernelGGL(kdft,    dim3(1), dim3(256), 0, stream, v, o);
}

// Round 2
// 122.349 us; speedup vs baseline: 1.0573x; 1.0022x over previous
//
#include <hip/hip_runtime.h>
#include <math.h>

#define LL 8
#define AA 4
#define DD 256
#define KF 129            // frequencies 0..128
#define KH 128            // complex-path frequencies 0..127; k=128 handled as real
#define NCHUNK 512
#define CLEN 32           // 16384 / 512
#define NE 44             // stored entries per operator (rows 1..8)
#define NE1 45            // including implicit row 0 (= e0)
#define LSTR 45           // LDS stride in kreduce: odd -> conflict-free b64

#define IDX(l,l1) ((((l)*((l)+1))/2) + (l1))

// ws layout in floats (~23.2 MB)
#define Q_OFF      0
#define OPST_OFF   (32 * KF * 2)                         // 8,256
#define OPS128_OFF (OPST_OFF + KH * NCHUNK * NE * 2)     // + 5,767,168
#define V_OFF      (OPS128_OFF + NCHUNK * NE)            // + 22,528
#define CNT_OFF    (V_OFF + 2 * KF + 2)                  // int counter slot

// T-space rescale: S_d[l] = T_d[l] / C(d,l).  Output row L needs 1/C(16384,8).
__device__ __forceinline__ float invCN8() {
  constexpr double c = (16384.0 * 16383.0 * 16382.0 * 16381.0 *
                        16380.0 * 16379.0 * 16378.0 * 16377.0) / 40320.0;
  return (float)(1.0 / c);
}

// ---------------- kernel 0: Q[l][c][k] = (2*sigmoid(logit)-1) * DFT_k(softmax(hash_emb[l,c,:])) ----
__global__ __launch_bounds__(256) void kq(const float* __restrict__ hemb,
                                          const float* __restrict__ slog,
                                          float* __restrict__ Q,
                                          int* __restrict__ cnt) {
  const int b = blockIdx.x;   // b = l*4 + c
  const int t = threadIdx.x;  // 0..255
  if (b == 0 && t == 0)
    __hip_atomic_store(cnt, 0, __ATOMIC_RELEASE, __HIP_MEMORY_SCOPE_AGENT);
  __shared__ float sh[DD];
  __shared__ float red[256];
  __shared__ float2 tw[256];
  {
    float sn, cs;
    __sincosf((float)t * (-0.0245436926061702596754894014319f), &sn, &cs); // -2*pi/256
    tw[t] = make_float2(cs, sn);
  }
  float h = hemb[b * DD + t];
  red[t] = h; __syncthreads();
  for (int off = 128; off > 0; off >>= 1) {
    if (t < off) red[t] = fmaxf(red[t], red[t + off]);
    __syncthreads();
  }
  float mx = red[0]; __syncthreads();
  float e = expf(h - mx);
  red[t] = e; __syncthreads();
  for (int off = 128; off > 0; off >>= 1) {
    if (t < off) red[t] += red[t + off];
    __syncthreads();
  }
  float s = red[0];
  sh[t] = e / s;
  __syncthreads();
  if (t < KF) {
    float cr = 0.0f, ci = 0.0f;
    for (int j = 0; j < DD; ++j) {
      const int m = (t * j) & 255;
      const float2 w = tw[m];
      const float p = sh[j];
      cr = fmaf(p, w.x, cr);
      ci = fmaf(p, w.y, ci);
    }
    const float sl = slog[b];
    const float sg = 1.0f / (1.0f + expf(-sl));
    const float q = fmaf(2.0f, sg, -1.0f);   // 2*sigmoid - 1
    Q[(b * KF + t) * 2 + 0] = q * cr;
    Q[(b * KF + t) * 2 + 1] = q * ci;
  }
}

// ---------------- T-space per-step operator update: T[l] += Q_l (x) T[l-1] -------------------
// Diagonal is invariant (=1); row 0 invariant. 36 complex fma per step.
template <int CC>
__device__ __forceinline__ void tstep(float (&Gr)[NE1], float (&Gi)[NE1],
                                      const float (&Qr)[LL][AA], const float (&Qi)[LL][AA]) {
#pragma unroll
  for (int l = LL; l >= 1; --l) {          // descending: row l reads OLD row l-1
    const float qr = Qr[l - 1][CC];
    const float qi = Qi[l - 1][CC];
#pragma unroll
    for (int l1 = 0; l1 < l; ++l1) {
      const float hr = Gr[IDX(l - 1, l1)];
      const float hi = Gi[IDX(l - 1, l1)];
      float gr = Gr[IDX(l, l1)];
      float gi = Gi[IDX(l, l1)];
      gr = fmaf(qr, hr, gr);
      gr = fmaf(-qi, hi, gr);
      gi = fmaf(qr, hi, gi);
      gi = fmaf(qi, hr, gi);
      Gr[IDX(l, l1)] = gr;
      Gi[IDX(l, l1)] = gi;
    }
  }
}

// ---------------- kernel 1: chunk transfer operators (T space, transposed output [k][p][e]) --
// blocks 0..1023: (chunk p = blk>>1, k = (blk&1)*64 + tid), complex path
// blocks 1024..1031: k=128 real path, lane = chunk; output [p][e]
__global__ __launch_bounds__(64) void kchunk(const int* __restrict__ seq,
                                             const float* __restrict__ Q,
                                             float* __restrict__ opsT,
                                             float* __restrict__ ops128T) {
  const int blk = blockIdx.x;
  const int t = threadIdx.x;
  __shared__ __align__(16) float sbuf[64 * NE * 2];   // 22528 B staging
  if (blk < NCHUNK * 2) {
    const int p = blk >> 1;
    const int k = (blk & 1) * 64 + t;    // 0..127
    float Qr[LL][AA], Qi[LL][AA];
    const float2* Q2 = (const float2*)Q;
#pragma unroll
    for (int lc = 0; lc < LL * AA; ++lc) {
      const float2 q = Q2[lc * KF + k];
      Qr[lc >> 2][lc & 3] = q.x;
      Qi[lc >> 2][lc & 3] = q.y;
    }
    float Gr[NE1], Gi[NE1];
#pragma unroll
    for (int e = 0; e < NE1; ++e) { Gr[e] = 0.0f; Gi[e] = 0.0f; }
#pragma unroll
    for (int l = 0; l <= LL; ++l) Gr[IDX(l, l)] = 1.0f;   // T-op = I

    const int base = p * CLEN;
    const int myc = seq[base + (t & 31)];   // whole chunk in registers, lane-parallel
    for (int s2 = 0; s2 < CLEN; ++s2) {
      const int c = __builtin_amdgcn_readlane(myc, s2);   // SGPR -> scalar switch, no load
      switch (c) {
        case 0:  tstep<0>(Gr, Gi, Qr, Qi); break;
        case 1:  tstep<1>(Gr, Gi, Qr, Qi); break;
        case 2:  tstep<2>(Gr, Gi, Qr, Qi); break;
        default: tstep<3>(Gr, Gi, Qr, Qi); break;
      }
    }
    // stage and write transposed: opsT[k][p][e] (352 B contiguous per (k,p))
    float2* ob = (float2*)sbuf;
#pragma unroll
    for (int e = 0; e < NE; ++e) ob[t * NE + e] = make_float2(Gr[e + 1], Gi[e + 1]);
    __syncthreads();
    const int k0 = (blk & 1) * 64;
    const float4* lb = (const float4*)sbuf;
    for (int it = 0; it < 22; ++it) {          // 64 segs * 22 float4 = 1408
      const int gid = it * 64 + t;
      const int sseg = gid / 22;
      const int u = gid - sseg * 22;
      float4* dst = (float4*)(opsT + ((size_t)(k0 + sseg) * NCHUNK + p) * (NE * 2));
      dst[u] = lb[gid];
    }
  } else {
    // k = 128 (Nyquist): Q is real there; lane = chunk index
    const int p = (blk - NCHUNK * 2) * 64 + t;   // 0..511
    float Q8[LL][AA];
#pragma unroll
    for (int lc = 0; lc < LL * AA; ++lc) Q8[lc >> 2][lc & 3] = Q[(lc * KF + KH) * 2 + 0];
    float G[NE1];
#pragma unroll
    for (int e = 0; e < NE1; ++e) G[e] = 0.0f;
#pragma unroll
    for (int l = 0; l <= LL; ++l) G[IDX(l, l)] = 1.0f;

    const int base = p * CLEN;
    for (int s2 = 0; s2 < CLEN; ++s2) {
      const int c = seq[base + s2];           // per-lane symbol
      float Qs[LL];
#pragma unroll
      for (int l = 0; l < LL; ++l) {
        const float qa = (c & 1) ? Q8[l][1] : Q8[l][0];
        const float qb = (c & 1) ? Q8[l][3] : Q8[l][2];
        Qs[l] = (c & 2) ? qb : qa;
      }
#pragma unroll
      for (int l = LL; l >= 1; --l) {
        const float q = Qs[l - 1];
#pragma unroll
        for (int l1 = 0; l1 < l; ++l1)
          G[IDX(l, l1)] = fmaf(q, G[IDX(l - 1, l1)], G[IDX(l, l1)]);
      }
    }
    // stage and write [p][e] (176 B contiguous per p)
    float* obr = sbuf;
#pragma unroll
    for (int e = 0; e < NE; ++e) obr[t * NE + e] = G[e + 1];
    __syncthreads();
    const int pbase = (blk - NCHUNK * 2) * 64;
    const float4* lbr = (const float4*)sbuf;
    for (int it = 0; it < 11; ++it) {          // 64 segs * 11 float4 = 704
      const int gid = it * 64 + t;
      const int sseg = gid / 11;
      const int u = gid - sseg * 11;
      float4* dst = (float4*)(ops128T + (size_t)(pbase + sseg) * NE);
      dst[u] = lbr[gid];
    }
  }
}

// ---------------- kernel 2: per-frequency full reduction 512 -> v[k]; last block does DFT ----
// block k<128: complex tree; block 128: real (Nyquist) tree
__global__ __launch_bounds__(128) void kreduce(const float* __restrict__ opsT,
                                               const float* __restrict__ ops128T,
                                               float* __restrict__ v,
                                               int* __restrict__ cnt,
                                               float* __restrict__ out) {
  const int k = blockIdx.x;
  const int j = threadIdx.x;
  __shared__ __align__(16) float lds[128 * LSTR * 2];   // 46080 B
  if (k < KH) {
    float2* Lc = (float2*)lds;
    float Ar[NE1], Ai[NE1], Br[NE1], Bi[NE1];
    Ar[0] = 1.0f; Ai[0] = 0.0f; Br[0] = 1.0f; Bi[0] = 0.0f;
    // L1: factor-4 from global (ops 4j..4j+3), A = Op3*Op2*Op1*Op0
    {
      const float4* s0 = (const float4*)(opsT + ((size_t)k * NCHUNK + 4 * j) * (NE * 2));
#pragma unroll
      for (int u = 0; u < 22; ++u) {
        const float4 x = s0[u];
        Ar[2 * u + 1] = x.x; Ai[2 * u + 1] = x.y;
        Ar[2 * u + 2] = x.z; Ai[2 * u + 2] = x.w;
      }
      for (int jj = 1; jj < 4; ++jj) {
        const float4* sB = (const float4*)(opsT + ((size_t)k * NCHUNK + 4 * j + jj) * (NE * 2));
#pragma unroll
        for (int u = 0; u < 22; ++u) {
          const float4 x = sB[u];
          Br[2 * u + 1] = x.x; Bi[2 * u + 1] = x.y;
          Br[2 * u + 2] = x.z; Bi[2 * u + 2] = x.w;
        }
#pragma unroll
        for (int l2 = LL; l2 >= 1; --l2) {
#pragma unroll
          for (int l1 = 0; l1 <= l2; ++l1) {
            float cr = 0.0f, ci = 0.0f;
#pragma unroll
            for (int m = l1; m <= l2; ++m) {
              const float br = Br[IDX(l2, m)], bi = Bi[IDX(l2, m)];
              const float ar = Ar[IDX(m, l1)], ai = Ai[IDX(m, l1)];
              cr = fmaf(br, ar, cr); cr = fmaf(-bi, ai, cr);
              ci = fmaf(br, ai, ci); ci = fmaf(bi, ar, ci);
            }
            Ar[IDX(l2, l1)] = cr; Ai[IDX(l2, l1)] = ci;
          }
        }
      }
#pragma unroll
      for (int e = 0; e < NE; ++e) Lc[j * LSTR + e] = make_float2(Ar[e + 1], Ai[e + 1]);
    }
    __syncthreads();
    // in-place factor-2 levels: 128->64->32->16->8
    for (int n = 64; n >= 8; n >>= 1) {
      const bool act = (j < n);
      if (act) {
#pragma unroll
        for (int e = 0; e < NE; ++e) { const float2 x = Lc[(2 * j) * LSTR + e];     Ar[e + 1] = x.x; Ai[e + 1] = x.y; }
#pragma unroll
        for (int e = 0; e < NE; ++e) { const float2 x = Lc[(2 * j + 1) * LSTR + e]; Br[e + 1] = x.x; Bi[e + 1] = x.y; }
#pragma unroll
        for (int l2 = LL; l2 >= 1; --l2) {
#pragma unroll
          for (int l1 = 0; l1 <= l2; ++l1) {
            float cr = 0.0f, ci = 0.0f;
#pragma unroll
            for (int m = l1; m <= l2; ++m) {
              const float br = Br[IDX(l2, m)], bi = Bi[IDX(l2, m)];
              const float ar = Ar[IDX(m, l1)], ai = Ai[IDX(m, l1)];
              cr = fmaf(br, ar, cr); cr = fmaf(-bi, ai, cr);
              ci = fmaf(br, ai, ci); ci = fmaf(bi, ar, ci);
            }
            Ar[IDX(l2, l1)] = cr; Ai[IDX(l2, l1)] = ci;
          }
        }
      }
      __syncthreads();
      if (act) {
#pragma unroll
        for (int e = 0; e < NE; ++e) Lc[j * LSTR + e] = make_float2(Ar[e + 1], Ai[e + 1]);
      }
      __syncthreads();
    }
    // apply 8 remaining ops to e0 (wave 0; lane l computes row l, shfl-broadcast)
    if (j < 64) {
      float sr[LL + 1], si[LL + 1];
      sr[0] = 1.0f; si[0] = 0.0f;
#pragma unroll
      for (int l = 1; l <= LL; ++l) { sr[l] = 0.0f; si[l] = 0.0f; }
      for (int g = 0; g < 8; ++g) {
        float nr = 0.0f, ni = 0.0f;
        if (j >= 1 && j <= LL) {
          const int rowbase = g * LSTR + ((j * (j + 1)) >> 1) - 1;  // entry IDX(j,0)-1
#pragma unroll
          for (int l1 = 0; l1 <= LL; ++l1) {
            if (l1 <= j) {
              const float2 bv = Lc[rowbase + l1];
              nr = fmaf(bv.x, sr[l1], nr); nr = fmaf(-bv.y, si[l1], nr);
              ni = fmaf(bv.x, si[l1], ni); ni = fmaf(bv.y, sr[l1], ni);
            }
          }
        }
#pragma unroll
        for (int l = 1; l <= LL; ++l) { sr[l] = __shfl(nr, l); si[l] = __shfl(ni, l); }
      }
      if (j == 0) {
        __hip_atomic_store(&v[2 * k],     sr[LL], __ATOMIC_RELEASE, __HIP_MEMORY_SCOPE_AGENT);
        __hip_atomic_store(&v[2 * k + 1], si[LL], __ATOMIC_RELEASE, __HIP_MEMORY_SCOPE_AGENT);
      }
    }
  } else {
    // real path (k = 128)
    float* Lr = lds;
    float A[NE1], B[NE1];
    A[0] = 1.0f; B[0] = 1.0f;
    {
      const float4* s0 = (const float4*)(ops128T + (size_t)(4 * j) * NE);
#pragma unroll
      for (int u = 0; u < 11; ++u) {
        const float4 x = s0[u];
        A[4 * u + 1] = x.x; A[4 * u + 2] = x.y; A[4 * u + 3] = x.z; A[4 * u + 4] = x.w;
      }
      for (int jj = 1; jj < 4; ++jj) {
        const float4* sB = (const float4*)(ops128T + (size_t)(4 * j + jj) * NE);
#pragma unroll
        for (int u = 0; u < 11; ++u) {
          const float4 x = sB[u];
          B[4 * u + 1] = x.x; B[4 * u + 2] = x.y; B[4 * u + 3] = x.z; B[4 * u + 4] = x.w;
        }
#pragma unroll
        for (int l2 = LL; l2 >= 1; --l2) {
#pragma unroll
          for (int l1 = 0; l1 <= l2; ++l1) {
            float cr = 0.0f;
#pragma unroll
            for (int m = l1; m <= l2; ++m) cr = fmaf(B[IDX(l2, m)], A[IDX(m, l1)], cr);
            A[IDX(l2, l1)] = cr;
          }
        }
      }
#pragma unroll
      for (int e = 0; e < NE; ++e) Lr[j * LSTR + e] = A[e + 1];
    }
    __syncthreads();
    for (int n = 64; n >= 8; n >>= 1) {
      const bool act = (j < n);
      if (act) {
#pragma unroll
        for (int e = 0; e < NE; ++e) A[e + 1] = Lr[(2 * j) * LSTR + e];
#pragma unroll
        for (int e = 0; e < NE; ++e) B[e + 1] = Lr[(2 * j + 1) * LSTR + e];
#pragma unroll
        for (int l2 = LL; l2 >= 1; --l2) {
#pragma unroll
          for (int l1 = 0; l1 <= l2; ++l1) {
            float cr = 0.0f;
#pragma unroll
            for (int m = l1; m <= l2; ++m) cr = fmaf(B[IDX(l2, m)], A[IDX(m, l1)], cr);
            A[IDX(l2, l1)] = cr;
          }
        }
      }
      __syncthreads();
      if (act) {
#pragma unroll
        for (int e = 0; e < NE; ++e) Lr[j * LSTR + e] = A[e + 1];
      }
      __syncthreads();
    }
    if (j < 64) {
      float s[LL + 1];
      s[0] = 1.0f;
#pragma unroll
      for (int l = 1; l <= LL; ++l) s[l] = 0.0f;
      for (int g = 0; g < 8; ++g) {
        float nr = 0.0f;
        if (j >= 1 && j <= LL) {
          const int rowbase = g * LSTR + ((j * (j + 1)) >> 1) - 1;
#pragma unroll
          for (int l1 = 0; l1 <= LL; ++l1)
            if (l1 <= j) nr = fmaf(Lr[rowbase + l1], s[l1], nr);
        }
#pragma unroll
        for (int l = 1; l <= LL; ++l) s[l] = __shfl(nr, l);
      }
      if (j == 0) {
        __hip_atomic_store(&v[2 * KH],     s[LL], __ATOMIC_RELEASE, __HIP_MEMORY_SCOPE_AGENT);
        __hip_atomic_store(&v[2 * KH + 1], 0.0f,  __ATOMIC_RELEASE, __HIP_MEMORY_SCOPE_AGENT);
      }
    }
  }

  // ---- last arriving block performs the inverse real DFT ----
  __shared__ int isLast;
  __syncthreads();
  if (j == 0) {
    const int old = __hip_atomic_fetch_add(cnt, 1, __ATOMIC_ACQ_REL, __HIP_MEMORY_SCOPE_AGENT);
    isLast = (old == KF - 1) ? 1 : 0;
  }
  __syncthreads();
  if (isLast) {
    __shared__ float2 twd[256];
    __shared__ float dvr[KF], dvi[KF];
    {
      float sn, cs;
      __sincosf((float)j * 0.0245436926061702596754894014319f, &sn, &cs);  // +2*pi/256
      twd[j] = make_float2(cs, sn);
      __sincosf((float)(j + 128) * 0.0245436926061702596754894014319f, &sn, &cs);
      twd[j + 128] = make_float2(cs, sn);
    }
    dvr[j] = __hip_atomic_load(&v[2 * j],     __ATOMIC_ACQUIRE, __HIP_MEMORY_SCOPE_AGENT);
    dvi[j] = __hip_atomic_load(&v[2 * j + 1], __ATOMIC_ACQUIRE, __HIP_MEMORY_SCOPE_AGENT);
    if (j == 0) {
      dvr[KH] = __hip_atomic_load(&v[2 * KH], __ATOMIC_ACQUIRE, __HIP_MEMORY_SCOPE_AGENT);
      dvi[KH] = 0.0f;
    }
    __syncthreads();
    const float sc = (1.0f / 256.0f) * invCN8();   // undo T-space rescale
#pragma unroll
    for (int rep = 0; rep < 2; ++rep) {
      const int jj = j + rep * 128;
      float sum = dvr[0] + ((jj & 1) ? -dvr[KH] : dvr[KH]);
      for (int k2 = 1; k2 < KH; ++k2) {
        const int m = (jj * k2) & 255;
        const float2 w = twd[m];
        sum = fmaf(2.0f * dvr[k2], w.x, sum);
        sum = fmaf(-2.0f * dvi[k2], w.y, sum);
      }
      out[jj] = sum * sc;
    }
  }
}

extern "C" void kernel_launch(void* const* d_in, const int* in_sizes, int n_in,
                              void* d_out, int out_size, void* d_ws, size_t ws_size,
                              hipStream_t stream) {
  (void)in_sizes; (void)n_in; (void)out_size; (void)ws_size;
  const int*   seq  = (const int*)d_in[0];
  const float* hemb = (const float*)d_in[1];
  const float* slog = (const float*)d_in[2];
  float* ws      = (float*)d_ws;
  float* Q       = ws + Q_OFF;
  float* opsT    = ws + OPST_OFF;
  float* ops128T = ws + OPS128_OFF;
  float* v       = ws + V_OFF;
  int*   cnt     = (int*)(ws + CNT_OFF);
  float* o       = (float*)d_out;

  hipLaunchKernelGGL(kq,      dim3(LL * AA), dim3(256), 0, stream, hemb, slog, Q, cnt);
  hipLaunchKernelGGL(kchunk,  dim3(NCHUNK * 2 + NCHUNK / 64), dim3(64), 0, stream, seq, Q, opsT, ops128T);
  hipLaunchKernelGGL(kreduce, dim3(KF), dim3(128), 0, stream, opsT, ops128T, v, cnt, o);
}

// Round 5
// 105.671 us; speedup vs baseline: 1.2242x; 1.1578x over previous
//
#include <hip/hip_runtime.h>
#include <math.h>

#define LL 8
#define AA 4
#define DD 256
#define KF 129            // frequencies 0..128
#define KH 128            // complex frequencies 0..127; k=128 real (Nyquist)
#define CLEN 32           // steps per chunk
#define NGR 128           // groups of 4 chunks (512 chunks total)
#define NES 36            // strict-lower entries, rows 1..8 (unit diagonal implicit)
#define LPAD 37           // padded slot stride (in elements)

typedef float v2f __attribute__((ext_vector_type(2)));

#define SIX(l2,l1) ((((l2)*((l2)-1))>>1) + (l1))     // l2 in 1..8, l1 < l2
#define SLOT(s)    ((s)*LPAD + ((s)>>1))             // kreduce complex slot base (v2f units)

// ws layout in floats (~4.8 MB)
#define Q_OFF   0
#define OPS_OFF (32*KF*2)                            // 8,256
#define OPS_SZ  (KH*NGR*NES*2)                       // 1,179,648
#define VH_OFF  (OPS_OFF + OPS_SZ)
#define V_OFF   (VH_OFF + 2*40)
#define CNT_OFF (V_OFF + 2*KF)                       // 2 ints

// T-space rescale: S_d[l] = T_d[l] / C(d,l); output row 8 needs 1/C(16384,8)
__device__ __forceinline__ float invCN8() {
  constexpr double c = (16384.0 * 16383.0 * 16382.0 * 16381.0 *
                        16380.0 * 16379.0 * 16378.0 * 16377.0) / 40320.0;
  return (float)(1.0 / c);
}

// acc += b (complex mul) a   -- packed: 2x v_pk_fma_f32
__device__ __forceinline__ v2f cfma(const v2f b, const v2f a, v2f acc) {
  const v2f bb = (v2f){ b.x,  b.x};
  const v2f bw = (v2f){-b.y,  b.y};
  const v2f as = (v2f){ a.y,  a.x};
  acc = __builtin_elementwise_fma(bb, a,  acc);
  acc = __builtin_elementwise_fma(bw, as, acc);
  return acc;
}

// ---------------- kernel 0: Q[l][c][k] -------------------------------------------------------
__global__ __launch_bounds__(256) void kq(const float* __restrict__ hemb,
                                          const float* __restrict__ slog,
                                          float* __restrict__ Q,
                                          int* __restrict__ cnt) {
  const int b = blockIdx.x;   // b = l*4 + c
  const int t = threadIdx.x;
  if (b == 0 && t == 0) {
    __hip_atomic_store(&cnt[0], 0, __ATOMIC_RELEASE, __HIP_MEMORY_SCOPE_AGENT);
    __hip_atomic_store(&cnt[1], 0, __ATOMIC_RELEASE, __HIP_MEMORY_SCOPE_AGENT);
  }
  __shared__ float sh[DD];
  __shared__ float red[256];
  __shared__ float2 tw[256];
  {
    float sn, cs;
    __sincosf((float)t * (-0.0245436926061702596754894014319f), &sn, &cs); // -2*pi/256
    tw[t] = make_float2(cs, sn);
  }
  float h = hemb[b * DD + t];
  red[t] = h; __syncthreads();
  for (int off = 128; off > 0; off >>= 1) {
    if (t < off) red[t] = fmaxf(red[t], red[t + off]);
    __syncthreads();
  }
  float mx = red[0]; __syncthreads();
  float e = expf(h - mx);
  red[t] = e; __syncthreads();
  for (int off = 128; off > 0; off >>= 1) {
    if (t < off) red[t] += red[t + off];
    __syncthreads();
  }
  float s = red[0];
  sh[t] = e / s;
  __syncthreads();
  if (t < KF) {
    float cr = 0.0f, ci = 0.0f;
    for (int j = 0; j < DD; ++j) {
      const int m = (t * j) & 255;
      const float2 w = tw[m];
      const float p = sh[j];
      cr = fmaf(p, w.x, cr);
      ci = fmaf(p, w.y, ci);
    }
    const float sl = slog[b];
    const float sg = 1.0f / (1.0f + expf(-sl));
    const float q = fmaf(2.0f, sg, -1.0f);
    Q[(b * KF + t) * 2 + 0] = q * cr;
    Q[(b * KF + t) * 2 + 1] = q * ci;
  }
}

// ---------------- packed T-space step: G[l][l1] += Q_l (x) G[l-1][l1], unit diag -------------
template <int CC>
__device__ __forceinline__ void tstep2(v2f (&G)[NES],
                                       const v2f (&QA)[LL][AA], const v2f (&QB)[LL][AA]) {
#pragma unroll
  for (int l = LL; l >= 1; --l) {          // descending: row l reads OLD row l-1
    const v2f qa = QA[l - 1][CC];          // (qr, qr)
    const v2f qb = QB[l - 1][CC];          // (-qi, qi)
    { // l1 = l-1 term: H = unit diag: G += (qr, qi)
      v2f g = G[SIX(l, l - 1)];
      g.x += qa.x; g.y += qb.y;
      G[SIX(l, l - 1)] = g;
    }
#pragma unroll
    for (int l1 = 0; l1 < l - 1; ++l1) {
      const v2f H  = G[SIX(l - 1, l1)];
      const v2f Hs = (v2f){H.y, H.x};
      v2f g = G[SIX(l, l1)];
      g = __builtin_elementwise_fma(qa, H,  g);
      g = __builtin_elementwise_fma(qb, Hs, g);
      G[SIX(l, l1)] = g;
    }
  }
}

// column-split product of unit-lower-triangular ops: C = B*A (B is the later op)
template <unsigned MASK>
__device__ __forceinline__ void prodCols(const v2f* __restrict__ A, const v2f* __restrict__ B,
                                         v2f (&o)[NES]) {
#pragma unroll
  for (int l1 = 0; l1 < 8; ++l1) {
    if ((MASK >> l1) & 1) {
#pragma unroll
      for (int l2 = l1 + 1; l2 <= 8; ++l2) {
        v2f acc = A[SIX(l2, l1)] + B[SIX(l2, l1)];
#pragma unroll
        for (int m = l1 + 1; m < l2; ++m) acc = cfma(B[SIX(l2, m)], A[SIX(m, l1)], acc);
        o[SIX(l2, l1)] = acc;
      }
    }
  }
}

template <unsigned MASK>
__device__ __forceinline__ void writeCols(v2f* __restrict__ D, const v2f (&o)[NES]) {
#pragma unroll
  for (int l1 = 0; l1 < 8; ++l1) {
    if ((MASK >> l1) & 1) {
#pragma unroll
      for (int l2 = l1 + 1; l2 <= 8; ++l2) D[SIX(l2, l1)] = o[SIX(l2, l1)];
    }
  }
}

// real (Nyquist) full product, strict-lower unit-triangular
__device__ __forceinline__ void prodR(const float* __restrict__ A, const float* __restrict__ B,
                                      float (&o)[NES]) {
#pragma unroll
  for (int l1 = 0; l1 < 8; ++l1) {
#pragma unroll
    for (int l2 = l1 + 1; l2 <= 8; ++l2) {
      float acc = A[SIX(l2, l1)] + B[SIX(l2, l1)];
#pragma unroll
      for (int m = l1 + 1; m < l2; ++m) acc = fmaf(B[SIX(l2, m)], A[SIX(m, l1)], acc);
      o[SIX(l2, l1)] = acc;
    }
  }
}

// ---------------- kernel 1: group transfer operators (4 chunks/block, in-block combine) ------
// 256 blocks x 256 thr: block = (group g, k-half); wave w computes chunk 4g+w; combine in LDS.
__global__ __launch_bounds__(256, 1) void kchunk(const int* __restrict__ seq,
                                                 const float* __restrict__ Q,
                                                 float* __restrict__ opsT) {
  const int blk  = blockIdx.x;          // 0..255
  const int g    = blk >> 1;            // group 0..127
  const int half = blk & 1;
  const int t    = threadIdx.x;
  const int w    = t >> 6;              // wave 0..3
  const int lane = t & 63;
  const int k    = half * 64 + lane;

  __shared__ __align__(16) float shb[2 * 64 * LPAD * 2];   // two op-slot banks, 37888 B
  v2f* S0 = (v2f*)shb;                        // [64 slots][LPAD]
  v2f* S1 = S0 + 64 * LPAD;

  v2f QA[LL][AA], QB[LL][AA];
  const float2* Q2 = (const float2*)Q;
#pragma unroll
  for (int lc = 0; lc < LL * AA; ++lc) {
    const float2 q = Q2[lc * KF + k];
    QA[lc >> 2][lc & 3] = (v2f){ q.x, q.x};
    QB[lc >> 2][lc & 3] = (v2f){-q.y, q.y};
  }

  v2f G[NES];
#pragma unroll
  for (int e = 0; e < NES; ++e) G[e] = (v2f){0.f, 0.f};   // identity op

  const int chunk = g * 4 + w;
  const int base  = chunk * CLEN;
  const int myc   = seq[base + (lane & 31)];
  for (int s2 = 0; s2 < CLEN; ++s2) {
    const int c = __builtin_amdgcn_readlane(myc, s2);
    switch (c) {
      case 0:  tstep2<0>(G, QA, QB); break;
      case 1:  tstep2<1>(G, QA, QB); break;
      case 2:  tstep2<2>(G, QA, QB); break;
      default: tstep2<3>(G, QA, QB); break;
    }
  }

  // ---- in-block combine: P = O3*O2*O1*O0, 4-way column split across waves ----
  const v2f* Ab = S0 + lane * LPAD;
  const v2f* Bb = S1 + lane * LPAD;
  v2f* Db = S0 + lane * LPAD;
  v2f* Wb = S1 + lane * LPAD;
  v2f pc[NES];

  if (w == 0)      { for (int e = 0; e < NES; ++e) Db[e] = G[e]; }
  else if (w == 1) { for (int e = 0; e < NES; ++e) Wb[e] = G[e]; }
  __syncthreads();

  for (int r = 0; r < 3; ++r) {
    switch (w) {
      case 0:  prodCols<0x01>(Ab, Bb, pc); break;   // col {0}
      case 1:  prodCols<0x42>(Ab, Bb, pc); break;   // cols {1,6}
      case 2:  prodCols<0x14>(Ab, Bb, pc); break;   // cols {2,4}
      default: prodCols<0xA8>(Ab, Bb, pc); break;   // cols {3,5,7}
    }
    __syncthreads();
    switch (w) {
      case 0:  writeCols<0x01>(Db, pc); break;
      case 1:  writeCols<0x42>(Db, pc); break;
      case 2:  writeCols<0x14>(Db, pc); break;
      default: writeCols<0xA8>(Db, pc); break;
    }
    if ((r == 0 && w == 2) || (r == 1 && w == 3)) {
      for (int e = 0; e < NES; ++e) Wb[e] = G[e];
    }
    __syncthreads();
  }

  // staging copy S0 -> global opsT[k][g][e] (288 B per (k,g), contiguous in g for fixed k)
  float2* dst = (float2*)opsT;
  for (int it = 0; it < 9; ++it) {
    const int idx = it * 256 + t;           // 0..2303 = 64 ops * 36 entries
    const int o   = idx / 36;
    const int e   = idx - o * 36;
    const v2f x   = S0[o * LPAD + e];
    dst[((size_t)(half * 64 + o) * NGR + g) * NES + e] = make_float2(x.x, x.y);
  }
}

// ---------------- kernel 2: per-frequency reduction 128 -> v[k]; Nyquist; last block DFT -----
__global__ __launch_bounds__(256, 1) void kreduce(const float* __restrict__ opsT,
                                                  const int* __restrict__ seq,
                                                  const float* __restrict__ Q,
                                                  float* __restrict__ vh,
                                                  float* __restrict__ v,
                                                  int* __restrict__ cnt,
                                                  float* __restrict__ outp) {
  const int blk = blockIdx.x;    // 0..129
  const int t   = threadIdx.x;
  __shared__ __align__(16) float ldsf[9600];   // 38400 B

  if (blk < KH) {
    // ---------------- complex path, k = blk ----------------
    const int k = blk;
    v2f* L = (v2f*)ldsf;
    const float4* src4 = (const float4*)(opsT + (size_t)k * NGR * NES * 2);
    for (int it = 0; it < 9; ++it) {
      const int idx = it * 256 + t;        // 2304 float4 total
      const float4 x = src4[idx];
      const int o = idx / 18;              // 18 float4 per op
      const int u = idx - o * 18;
      L[SLOT(o) + 2 * u]     = (v2f){x.x, x.y};
      L[SLOT(o) + 2 * u + 1] = (v2f){x.z, x.w};
    }
    __syncthreads();

    const int w = t >> 6;
    const int j = t & 63;
    v2f pc[NES];
    for (int n = 64; n >= 8; n >>= 1) {    // 128->64->32->16->8 ops
      const bool act = (j < n);
      if (act) {
        const v2f* Ab = L + SLOT(2 * j);
        const v2f* Bb = L + SLOT(2 * j + 1);
        switch (w) {
          case 0:  prodCols<0x01>(Ab, Bb, pc); break;
          case 1:  prodCols<0x42>(Ab, Bb, pc); break;
          case 2:  prodCols<0x14>(Ab, Bb, pc); break;
          default: prodCols<0xA8>(Ab, Bb, pc); break;
        }
      }
      __syncthreads();
      if (act) {
        v2f* Db = L + SLOT(j);
        switch (w) {
          case 0:  writeCols<0x01>(Db, pc); break;
          case 1:  writeCols<0x42>(Db, pc); break;
          case 2:  writeCols<0x14>(Db, pc); break;
          default: writeCols<0xA8>(Db, pc); break;
        }
      }
      __syncthreads();
    }

    // apply 8 remaining ops to e0 (wave 0; lane l computes row l, shfl broadcast)
    if (t < 64) {
      v2f sv[LL + 1];
      sv[0] = (v2f){1.f, 0.f};
#pragma unroll
      for (int l = 1; l <= LL; ++l) sv[l] = (v2f){0.f, 0.f};
      for (int gg = 0; gg < 8; ++gg) {
        v2f nv = (v2f){0.f, 0.f};
        if (t >= 1 && t <= LL) {
          nv = sv[t];                               // unit diagonal
          const v2f* Bb = L + SLOT(gg);
          const int rb = (t * (t - 1)) >> 1;        // SIX(t, 0)
#pragma unroll
          for (int l1 = 0; l1 < 8; ++l1) {
            if (l1 < t) nv = cfma(Bb[rb + l1], sv[l1], nv);
          }
        }
#pragma unroll
        for (int l = 1; l <= LL; ++l) {
          sv[l].x = __shfl(nv.x, l);
          sv[l].y = __shfl(nv.y, l);
        }
      }
      if (t == 0) {
        __hip_atomic_store(&v[2 * k],     sv[LL].x, __ATOMIC_RELEASE, __HIP_MEMORY_SCOPE_AGENT);
        __hip_atomic_store(&v[2 * k + 1], sv[LL].y, __ATOMIC_RELEASE, __HIP_MEMORY_SCOPE_AGENT);
      }
    }
  } else {
    // ---------------- Nyquist (k=128, real): blocks 128,129 = halves ----------------
    const int half = blk - KH;
    float* Lr = ldsf;                       // [256 slots][LPAD] floats
    float Q8[LL][AA];
#pragma unroll
    for (int lc = 0; lc < LL * AA; ++lc) Q8[lc >> 2][lc & 3] = Q[(lc * KF + KH) * 2];

    float Gr[NES];
#pragma unroll
    for (int e = 0; e < NES; ++e) Gr[e] = 0.f;

    const int base = (half * 256 + t) * CLEN;
    int sym[CLEN];
    {
      const int4* sp = (const int4*)(seq + base);
#pragma unroll
      for (int u = 0; u < CLEN / 4; ++u) {
        const int4 x = sp[u];
        sym[4 * u + 0] = x.x; sym[4 * u + 1] = x.y;
        sym[4 * u + 2] = x.z; sym[4 * u + 3] = x.w;
      }
    }
#pragma unroll
    for (int s2 = 0; s2 < CLEN; ++s2) {
      const int c = sym[s2];
      float Qs[LL];
#pragma unroll
      for (int l = 0; l < LL; ++l) {
        const float qa = (c & 1) ? Q8[l][1] : Q8[l][0];
        const float qb = (c & 1) ? Q8[l][3] : Q8[l][2];
        Qs[l] = (c & 2) ? qb : qa;
      }
#pragma unroll
      for (int l = LL; l >= 1; --l) {
        Gr[SIX(l, l - 1)] += Qs[l - 1];
#pragma unroll
        for (int l1 = 0; l1 < l - 1; ++l1)
          Gr[SIX(l, l1)] = fmaf(Qs[l - 1], Gr[SIX(l - 1, l1)], Gr[SIX(l, l1)]);
      }
    }
#pragma unroll
    for (int e = 0; e < NES; ++e) Lr[t * LPAD + e] = Gr[e];
    __syncthreads();

    float po[NES];
    for (int n = 128; n >= 1; n >>= 1) {   // 256 -> 1
      const bool act = (t < n);
      if (act) prodR(Lr + (2 * t) * LPAD, Lr + (2 * t + 1) * LPAD, po);
      __syncthreads();
      if (act) { for (int e = 0; e < NES; ++e) Lr[t * LPAD + e] = po[e]; }
      __syncthreads();
    }
    if (t < NES)
      __hip_atomic_store(&vh[half * 40 + t], Lr[t], __ATOMIC_RELEASE, __HIP_MEMORY_SCOPE_AGENT);
    __syncthreads();
    if (t == 0) {
      const int o2 = __hip_atomic_fetch_add(&cnt[1], 1, __ATOMIC_ACQ_REL, __HIP_MEMORY_SCOPE_AGENT);
      if (o2 == 1) {
        // second arriving half: row 8, column 0 of H1*H0 (both unit-lower-triangular)
        float h0[LL + 1];
#pragma unroll
        for (int m = 1; m <= LL; ++m)
          h0[m] = __hip_atomic_load(&vh[0 + SIX(m, 0)], __ATOMIC_ACQUIRE, __HIP_MEMORY_SCOPE_AGENT);
        float acc = h0[LL] +
          __hip_atomic_load(&vh[40 + SIX(LL, 0)], __ATOMIC_ACQUIRE, __HIP_MEMORY_SCOPE_AGENT);
#pragma unroll
        for (int m = 1; m <= 7; ++m)
          acc = fmaf(__hip_atomic_load(&vh[40 + SIX(LL, m)], __ATOMIC_ACQUIRE, __HIP_MEMORY_SCOPE_AGENT),
                     h0[m], acc);
        __hip_atomic_store(&v[2 * KH],     acc,  __ATOMIC_RELEASE, __HIP_MEMORY_SCOPE_AGENT);
        __hip_atomic_store(&v[2 * KH + 1], 0.0f, __ATOMIC_RELEASE, __HIP_MEMORY_SCOPE_AGENT);
      }
    }
  }

  // ---- last arriving of 130 blocks performs the inverse real DFT ----
  __shared__ int isLast;
  __syncthreads();
  if (t == 0) {
    const int old = __hip_atomic_fetch_add(&cnt[0], 1, __ATOMIC_ACQ_REL, __HIP_MEMORY_SCOPE_AGENT);
    isLast = (old == 129) ? 1 : 0;
  }
  __syncthreads();
  if (isLast) {
    __shared__ float2 twd[256];
    __shared__ float dvr[KF], dvi[KF];
    {
      float sn, cs;
      __sincosf((float)t * 0.0245436926061702596754894014319f, &sn, &cs);  // +2*pi/256
      twd[t] = make_float2(cs, sn);
    }
    if (t < KF) {
      dvr[t] = __hip_atomic_load(&v[2 * t],     __ATOMIC_ACQUIRE, __HIP_MEMORY_SCOPE_AGENT);
      dvi[t] = __hip_atomic_load(&v[2 * t + 1], __ATOMIC_ACQUIRE, __HIP_MEMORY_SCOPE_AGENT);
    }
    if (t == 0) {  // self-reset so every dispatch (incl. rocprof replays) starts clean
      __hip_atomic_store(&cnt[0], 0, __ATOMIC_RELEASE, __HIP_MEMORY_SCOPE_AGENT);
      __hip_atomic_store(&cnt[1], 0, __ATOMIC_RELEASE, __HIP_MEMORY_SCOPE_AGENT);
    }
    __syncthreads();
    const float sc = (1.0f / 256.0f) * invCN8();   // undo T-space rescale
    float sum = dvr[0] + ((t & 1) ? -dvr[KH] : dvr[KH]);
    for (int k2 = 1; k2 < KH; ++k2) {
      const int m = (t * k2) & 255;
      const float2 wv = twd[m];
      sum = fmaf(2.0f * dvr[k2], wv.x, sum);
      sum = fmaf(-2.0f * dvi[k2], wv.y, sum);
    }
    outp[t] = sum * sc;
  }
}

extern "C" void kernel_launch(void* const* d_in, const int* in_sizes, int n_in,
                              void* d_out, int out_size, void* d_ws, size_t ws_size,
                              hipStream_t stream) {
  (void)in_sizes; (void)n_in; (void)out_size; (void)ws_size;
  const int*   seq  = (const int*)d_in[0];
  const float* hemb = (const float*)d_in[1];
  const float* slog = (const float*)d_in[2];
  float* ws   = (float*)d_ws;
  float* Q    = ws + Q_OFF;
  float* opsT = ws + OPS_OFF;
  float* vh   = ws + VH_OFF;
  float* v    = ws + V_OFF;
  int*   cnt  = (int*)(ws + CNT_OFF);
  float* o    = (float*)d_out;

  hipLaunchKernelGGL(kq,      dim3(LL * AA), dim3(256), 0, stream, hemb, slog, Q, cnt);
  hipLaunchKernelGGL(kchunk,  dim3(256),     dim3(256), 0, stream, seq, Q, opsT);
  hipLaunchKernelGGL(kreduce, dim3(130),     dim3(256), 0, stream, opsT, seq, Q, vh, v, cnt, o);
}